// Round 1
// baseline (568.134 us; speedup 1.0000x reference)
//
#include <hip/hip_runtime.h>

#define D 64

// ---------------------------------------------------------------------------
// 1) degree: deg[row[e]] += 1  (float counts are exact for deg < 2^24)
// ---------------------------------------------------------------------------
__global__ __launch_bounds__(256) void deg_kernel(const int* __restrict__ row,
                                                  int E,
                                                  float* __restrict__ deg) {
    int e = blockIdx.x * blockDim.x + threadIdx.x;
    if (e < E) atomicAdd(&deg[row[e]], 1.0f);
}

// ---------------------------------------------------------------------------
// 2) dinv_sqrt in place: deg[i] = deg[i] > 0 ? rsqrt(deg[i]) : 0
// ---------------------------------------------------------------------------
__global__ __launch_bounds__(256) void dinv_kernel(float* __restrict__ deg, int N) {
    int i = blockIdx.x * blockDim.x + threadIdx.x;
    if (i < N) {
        float d = deg[i];
        deg[i] = (d > 0.0f) ? rsqrtf(d) : 0.0f;
    }
}

// ---------------------------------------------------------------------------
// 3) xh = x @ W^T   (x: [N,64], W: [64,64] row-major (D_OUT, D_IN))
//    4 rows per 256-thread block; W staged in LDS with +1 pad (stride 65 ->
//    (col+k)%32 bank pattern, 2-way across the 64-lane wave = free).
//    x row broadcast from LDS (same-address = free).
// ---------------------------------------------------------------------------
__global__ __launch_bounds__(256) void linear_kernel(const float* __restrict__ x,
                                                     const float* __restrict__ W,
                                                     float* __restrict__ xh,
                                                     int N) {
    __shared__ float Wl[D][D + 1];
    __shared__ float xs[4][D];

    int tid = threadIdx.x;
    for (int i = tid; i < D * D; i += 256) {
        Wl[i >> 6][i & 63] = W[i];
    }

    int col = tid & 63;
    int rl  = tid >> 6;
    int r   = blockIdx.x * 4 + rl;
    if (r < N) xs[rl][col] = x[(size_t)r * D + col];
    __syncthreads();

    if (r < N) {
        float acc = 0.0f;
#pragma unroll
        for (int k = 0; k < D; ++k) {
            acc = fmaf(xs[rl][k], Wl[col][k], acc);
        }
        xh[(size_t)r * D + col] = acc;
    }
}

// ---------------------------------------------------------------------------
// 4) scatter SpMM: out[row_e] += dinv[row_e]*dinv[col_e] * xh[col_e]
//    One lane per (edge, feature): gid>>6 = edge, gid&63 = feature.
//    Each 64-lane wave handles exactly one edge -> xh gather and the
//    atomicAdd target are each one contiguous 256 B region (coalesced).
// ---------------------------------------------------------------------------
__global__ __launch_bounds__(256) void scatter_kernel(const int* __restrict__ ei,
                                                      int E,
                                                      const float* __restrict__ dinv,
                                                      const float* __restrict__ xh,
                                                      float* __restrict__ out) {
    long long gid = (long long)blockIdx.x * blockDim.x + threadIdx.x;
    int e = (int)(gid >> 6);
    if (e >= E) return;
    int c = (int)(gid & 63);

    int r  = ei[e];       // edge_index[0][e]
    int cn = ei[E + e];   // edge_index[1][e]

    float w = dinv[r] * dinv[cn];
    float v = w * xh[(size_t)cn * D + c];
    atomicAdd(&out[(size_t)r * D + c], v);
}

extern "C" void kernel_launch(void* const* d_in, const int* in_sizes, int n_in,
                              void* d_out, int out_size, void* d_ws, size_t ws_size,
                              hipStream_t stream) {
    const int*   ei = (const int*)d_in[0];     // (2, E) flat: [0..E) rows, [E..2E) cols
    const float* x  = (const float*)d_in[1];   // (N, 64)
    const float* W  = (const float*)d_in[2];   // (64, 64)
    float* out = (float*)d_out;                // (N, 64)

    int E = in_sizes[0] / 2;
    int N = in_sizes[1] / D;

    // Workspace layout: [deg/dinv : N floats][pad to 256 B][xh : N*64 floats]
    float* deg = (float*)d_ws;
    size_t xh_off = ((size_t)N * sizeof(float) + 255) & ~(size_t)255;
    float* xh = (float*)((char*)d_ws + xh_off);

    hipMemsetAsync(d_ws, 0, (size_t)N * sizeof(float), stream);
    hipMemsetAsync(d_out, 0, (size_t)out_size * sizeof(float), stream);

    deg_kernel<<<(E + 255) / 256, 256, 0, stream>>>(ei, E, deg);
    dinv_kernel<<<(N + 255) / 256, 256, 0, stream>>>(deg, N);
    linear_kernel<<<(N + 3) / 4, 256, 0, stream>>>(x, W, xh, N);

    long long total = (long long)E * D;
    int blocks = (int)((total + 255) / 256);
    scatter_kernel<<<blocks, 256, 0, stream>>>(ei, E, deg, xh, out);
}

// Round 2
// 409.606 us; speedup vs baseline: 1.3870x; 1.3870x over previous
//
#include <hip/hip_runtime.h>

#define D 64

// ---------------------------------------------------------------------------
// K1: integer degree histogram over edge rows
// ---------------------------------------------------------------------------
__global__ __launch_bounds__(256) void deg_kernel(const int* __restrict__ row,
                                                  int E, int* __restrict__ deg) {
    int e = blockIdx.x * blockDim.x + threadIdx.x;
    if (e < E) atomicAdd(&deg[row[e]], 1);
}

// ---------------------------------------------------------------------------
// K2a: per-256-block sums of deg
// ---------------------------------------------------------------------------
__global__ __launch_bounds__(256) void scan_block_sums(const int* __restrict__ deg,
                                                       int N, int* __restrict__ bsum) {
    __shared__ int s[256];
    int i = blockIdx.x * 256 + threadIdx.x;
    s[threadIdx.x] = (i < N) ? deg[i] : 0;
    __syncthreads();
    for (int off = 128; off > 0; off >>= 1) {
        if (threadIdx.x < off) s[threadIdx.x] += s[threadIdx.x + off];
        __syncthreads();
    }
    if (threadIdx.x == 0) bsum[blockIdx.x] = s[0];
}

// ---------------------------------------------------------------------------
// K2b: single-block exclusive scan of block sums (nb <= 1024); also rowptr[N]=E
// ---------------------------------------------------------------------------
__global__ __launch_bounds__(1024) void scan_top(int* __restrict__ bsum, int nb,
                                                 int* __restrict__ rowptr, int N, int E) {
    __shared__ int s[1024];
    int t = threadIdx.x;
    int v = (t < nb) ? bsum[t] : 0;
    s[t] = v;
    __syncthreads();
    for (int off = 1; off < 1024; off <<= 1) {
        int add = (t >= off) ? s[t - off] : 0;
        __syncthreads();
        s[t] += add;
        __syncthreads();
    }
    if (t < nb) bsum[t] = s[t] - v;  // exclusive
    if (t == 0) rowptr[N] = E;
}

// ---------------------------------------------------------------------------
// K2c: rowptr[i] = exclusive scan of deg; dinv[i] = deg>0 ? rsqrt(deg) : 0
// ---------------------------------------------------------------------------
__global__ __launch_bounds__(256) void scan_final(const int* __restrict__ deg, int N,
                                                  const int* __restrict__ bsum,
                                                  int* __restrict__ rowptr,
                                                  float* __restrict__ dinv) {
    __shared__ int s[256];
    int t = threadIdx.x;
    int i = blockIdx.x * 256 + t;
    int v = (i < N) ? deg[i] : 0;
    s[t] = v;
    __syncthreads();
    for (int off = 1; off < 256; off <<= 1) {
        int add = (t >= off) ? s[t - off] : 0;
        __syncthreads();
        s[t] += add;
        __syncthreads();
    }
    if (i < N) {
        rowptr[i] = bsum[blockIdx.x] + s[t] - v;  // exclusive prefix
        dinv[i] = (v > 0) ? rsqrtf((float)v) : 0.0f;
    }
}

// ---------------------------------------------------------------------------
// K3: bucket-fill CSR column indices (cursor pre-zeroed)
// ---------------------------------------------------------------------------
__global__ __launch_bounds__(256) void fill_kernel(const int* __restrict__ ei, int E,
                                                   const int* __restrict__ rowptr,
                                                   int* __restrict__ cursor,
                                                   int* __restrict__ csr_col) {
    int e = blockIdx.x * blockDim.x + threadIdx.x;
    if (e < E) {
        int r = ei[e];
        int pos = rowptr[r] + atomicAdd(&cursor[r], 1);
        csr_col[pos] = ei[E + e];
    }
}

// ---------------------------------------------------------------------------
// K4: xh = x @ W^T. One wave per row, W in LDS (+1 pad -> (c+k)%32 banks,
//     2-way across wave64 = free). x row broadcast via __shfl, no loop syncs.
//     Grid-stride so W is staged once per block, not once per 4 rows.
// ---------------------------------------------------------------------------
__global__ __launch_bounds__(256) void linear_kernel(const float* __restrict__ x,
                                                     const float* __restrict__ W,
                                                     float* __restrict__ xh, int N) {
    __shared__ float Wl[D][D + 1];
    int tid = threadIdx.x;
    for (int i = tid; i < D * D; i += 256) Wl[i >> 6][i & 63] = W[i];
    __syncthreads();

    int c = tid & 63;
    int wl = tid >> 6;
    int stride = gridDim.x * 4;
    for (int r = blockIdx.x * 4 + wl; r < N; r += stride) {
        float xv = x[(size_t)r * D + c];
        float acc = 0.0f;
#pragma unroll
        for (int k = 0; k < D; ++k) acc = fmaf(__shfl(xv, k), Wl[c][k], acc);
        xh[(size_t)r * D + c] = acc;
    }
}

// ---------------------------------------------------------------------------
// K5: gather SpMM. One wave per row; lane = feature. Cols + dinv loaded
//     64-wide then broadcast by __shfl; per edge one coalesced 256 B gather
//     of xh[cn]; register accumulate; single coalesced store per row.
//     Writes EVERY row (zero rows write 0) -> no d_out memset needed.
// ---------------------------------------------------------------------------
__global__ __launch_bounds__(256) void spmm_kernel(const int* __restrict__ rowptr,
                                                   const int* __restrict__ csr_col,
                                                   const float* __restrict__ dinv,
                                                   const float* __restrict__ xh,
                                                   float* __restrict__ out, int N) {
    int r = (blockIdx.x * 256 + threadIdx.x) >> 6;
    int c = threadIdx.x & 63;
    if (r >= N) return;

    int start = rowptr[r];
    int end   = rowptr[r + 1];
    float dr  = dinv[r];
    float acc = 0.0f;

    for (int j0 = start; j0 < end; j0 += 64) {
        int n = end - j0;
        if (n > 64) n = 64;
        int cn = 0;
        float dv = 0.0f;
        if (c < n) {
            cn = csr_col[j0 + c];
            dv = dinv[cn];
        }
        for (int k = 0; k < n; ++k) {
            int   cnk = __shfl(cn, k);
            float wk  = __shfl(dv, k);
            acc = fmaf(dr * wk, xh[(size_t)cnk * D + c], acc);
        }
    }
    out[(size_t)r * D + c] = acc;
}

extern "C" void kernel_launch(void* const* d_in, const int* in_sizes, int n_in,
                              void* d_out, int out_size, void* d_ws, size_t ws_size,
                              hipStream_t stream) {
    const int*   ei = (const int*)d_in[0];   // (2,E) flat: [0..E) rows, [E..2E) cols
    const float* x  = (const float*)d_in[1]; // (N,64)
    const float* W  = (const float*)d_in[2]; // (64,64)
    float* out = (float*)d_out;              // (N,64)

    int E = in_sizes[0] / 2;
    int N = in_sizes[1] / D;
    int nb = (N + 255) / 256;  // scan blocks (391 for N=100000)

    // Workspace layout (256 B aligned slices)
    char* p = (char*)d_ws;
    size_t off = 0;
    auto take = [&](size_t bytes) -> char* {
        char* cur = p + off;
        off = (off + bytes + 255) & ~(size_t)255;
        return cur;
    };
    int*   degi    = (int*)take((size_t)N * 4);
    float* dinv    = (float*)take((size_t)N * 4);
    int*   rowptr  = (int*)take((size_t)(N + 1) * 4);
    int*   bsum    = (int*)take((size_t)nb * 4);
    int*   cursor  = (int*)take((size_t)N * 4);
    int*   csr_col = (int*)take((size_t)E * 4);
    float* xh      = (float*)take((size_t)N * D * 4);
    (void)ws_size;

    hipMemsetAsync(degi, 0, (size_t)N * 4, stream);
    hipMemsetAsync(cursor, 0, (size_t)N * 4, stream);

    deg_kernel<<<(E + 255) / 256, 256, 0, stream>>>(ei, E, degi);
    scan_block_sums<<<nb, 256, 0, stream>>>(degi, N, bsum);
    scan_top<<<1, 1024, 0, stream>>>(bsum, nb, rowptr, N, E);
    scan_final<<<nb, 256, 0, stream>>>(degi, N, bsum, rowptr, dinv);
    fill_kernel<<<(E + 255) / 256, 256, 0, stream>>>(ei, E, rowptr, cursor, csr_col);
    linear_kernel<<<1024, 256, 0, stream>>>(x, W, xh, N);
    spmm_kernel<<<(N * 64 + 255) / 256, 256, 0, stream>>>(rowptr, csr_col, dinv, xh, out, N);
}

// Round 3
// 345.003 us; speedup vs baseline: 1.6468x; 1.1873x over previous
//
#include <hip/hip_runtime.h>
#include <hip/hip_fp16.h>

#define D 64

// ---------------------------------------------------------------------------
// K1: integer degree histogram over edge rows
// ---------------------------------------------------------------------------
__global__ __launch_bounds__(256) void deg_kernel(const int* __restrict__ row,
                                                  int E, int* __restrict__ deg) {
    int e = blockIdx.x * blockDim.x + threadIdx.x;
    if (e < E) atomicAdd(&deg[row[e]], 1);
}

// ---------------------------------------------------------------------------
// K2a: per-256-block sums of deg
// ---------------------------------------------------------------------------
__global__ __launch_bounds__(256) void scan_block_sums(const int* __restrict__ deg,
                                                       int N, int* __restrict__ bsum) {
    __shared__ int s[256];
    int i = blockIdx.x * 256 + threadIdx.x;
    s[threadIdx.x] = (i < N) ? deg[i] : 0;
    __syncthreads();
    for (int off = 128; off > 0; off >>= 1) {
        if (threadIdx.x < off) s[threadIdx.x] += s[threadIdx.x + off];
        __syncthreads();
    }
    if (threadIdx.x == 0) bsum[blockIdx.x] = s[0];
}

// ---------------------------------------------------------------------------
// K2b: single-block exclusive scan of block sums (nb <= 1024)
// ---------------------------------------------------------------------------
__global__ __launch_bounds__(1024) void scan_top(int* __restrict__ bsum, int nb) {
    __shared__ int s[1024];
    int t = threadIdx.x;
    int v = (t < nb) ? bsum[t] : 0;
    s[t] = v;
    __syncthreads();
    for (int off = 1; off < 1024; off <<= 1) {
        int add = (t >= off) ? s[t - off] : 0;
        __syncthreads();
        s[t] += add;
        __syncthreads();
    }
    if (t < nb) bsum[t] = s[t] - v;  // exclusive
}

// ---------------------------------------------------------------------------
// K2c: rowptr[i] = exclusive prefix of deg; dinv[i] = deg>0 ? rsqrt(deg) : 0
//      (fill_kernel will atomically bump rowptr[i] up to the row END)
// ---------------------------------------------------------------------------
__global__ __launch_bounds__(256) void scan_final(const int* __restrict__ deg, int N,
                                                  const int* __restrict__ bsum,
                                                  int* __restrict__ rowptr,
                                                  float* __restrict__ dinv) {
    __shared__ int s[256];
    int t = threadIdx.x;
    int i = blockIdx.x * 256 + t;
    int v = (i < N) ? deg[i] : 0;
    s[t] = v;
    __syncthreads();
    for (int off = 1; off < 256; off <<= 1) {
        int add = (t >= off) ? s[t - off] : 0;
        __syncthreads();
        s[t] += add;
        __syncthreads();
    }
    if (i < N) {
        rowptr[i] = bsum[blockIdx.x] + s[t] - v;  // exclusive prefix
        dinv[i] = (v > 0) ? rsqrtf((float)v) : 0.0f;
    }
}

// ---------------------------------------------------------------------------
// K3: bucket-fill. atomicAdd on rowptr[r] itself returns the slot AND leaves
//     rowptr[r] == end-of-row-r after the pass (start = rowptr[r-1]).
//     One memory op per edge instead of read-rowptr + atomic-cursor.
// ---------------------------------------------------------------------------
__global__ __launch_bounds__(256) void fill_kernel(const int* __restrict__ ei, int E,
                                                   int* __restrict__ rowptr,
                                                   int* __restrict__ csr_col) {
    int e = blockIdx.x * blockDim.x + threadIdx.x;
    if (e < E) {
        int r = ei[e];
        int pos = atomicAdd(&rowptr[r], 1);
        csr_col[pos] = ei[E + e];
    }
}

// ---------------------------------------------------------------------------
// K4: xh[r][c] = dinv[r] * sum_k x[r][k] * W[c][k], stored as fp16.
//     Lane c holds W row c in 64 VGPRs (loaded once); per row: one coalesced
//     x load, then 64 v_fmac with the broadcast via SALU v_readlane (no LDS
//     pipe at all). 4 accumulators break the fmac dependence chain.
// ---------------------------------------------------------------------------
__global__ __launch_bounds__(256) void linear_kernel(const float* __restrict__ x,
                                                     const float* __restrict__ W,
                                                     const float* __restrict__ dinv,
                                                     __half* __restrict__ xh, int N) {
    int c  = threadIdx.x & 63;
    int wl = threadIdx.x >> 6;

    float w[D];
    const float4* W4 = (const float4*)(W + (size_t)c * D);
#pragma unroll
    for (int q = 0; q < D / 4; ++q) {
        float4 t = W4[q];
        w[4 * q + 0] = t.x; w[4 * q + 1] = t.y;
        w[4 * q + 2] = t.z; w[4 * q + 3] = t.w;
    }

    int stride = gridDim.x * 4;
    for (int r = blockIdx.x * 4 + wl; r < N; r += stride) {
        float xv = x[(size_t)r * D + c];
        float a0 = 0.f, a1 = 0.f, a2 = 0.f, a3 = 0.f;
#pragma unroll
        for (int k = 0; k < D; k += 4) {
            a0 = fmaf(__uint_as_float(__builtin_amdgcn_readlane(__float_as_uint(xv), k + 0)), w[k + 0], a0);
            a1 = fmaf(__uint_as_float(__builtin_amdgcn_readlane(__float_as_uint(xv), k + 1)), w[k + 1], a1);
            a2 = fmaf(__uint_as_float(__builtin_amdgcn_readlane(__float_as_uint(xv), k + 2)), w[k + 2], a2);
            a3 = fmaf(__uint_as_float(__builtin_amdgcn_readlane(__float_as_uint(xv), k + 3)), w[k + 3], a3);
        }
        float acc = (a0 + a1) + (a2 + a3);
        xh[(size_t)r * D + c] = __float2half(dinv[r] * acc);
    }
}

// ---------------------------------------------------------------------------
// K5: gather SpMM, one wave per row. xh is fp16 pre-scaled by dinv[col], with
//     a zero sentinel row at index N (chunk padding -> clean unroll-by-8).
//     Half-wave split: lanes 0-31 do even edges, 32-63 odd edges, each lane
//     loads a __half2 (features 2f,2f+1) -> 128 B coalesced per edge.
//     Column broadcast via __shfl (ds_bpermute); 4 gathers in flight.
//     Writes every row -> no d_out memset.
// ---------------------------------------------------------------------------
__global__ __launch_bounds__(256) void spmm_kernel(const int* __restrict__ rowptr_end,
                                                   const int* __restrict__ csr_col,
                                                   const float* __restrict__ dinv,
                                                   const __half2* __restrict__ xh2,
                                                   float2* __restrict__ out2, int N) {
    int r = (blockIdx.x * 256 + threadIdx.x) >> 6;
    if (r >= N) return;
    int c   = threadIdx.x & 63;
    int sub = c >> 5;   // 0 = even edges, 1 = odd edges
    int f   = c & 31;   // feature-pair index

    int end   = rowptr_end[r];
    int start = (r == 0) ? 0 : rowptr_end[r - 1];
    float dr  = dinv[r];

    float ax = 0.f, ay = 0.f;
    for (int j0 = start; j0 < end; j0 += 64) {
        int n = end - j0;
        if (n > 64) n = 64;
        int cn_reg = (c < n) ? csr_col[j0 + c] : N;   // N = zero sentinel row
        int n8 = (n + 7) & ~7;
        for (int k = 0; k < n8; k += 8) {
            int e0 = __shfl(cn_reg, k + 0 + sub);
            int e1 = __shfl(cn_reg, k + 2 + sub);
            int e2 = __shfl(cn_reg, k + 4 + sub);
            int e3 = __shfl(cn_reg, k + 6 + sub);
            float2 v0 = __half22float2(xh2[(size_t)e0 * 32 + f]);
            float2 v1 = __half22float2(xh2[(size_t)e1 * 32 + f]);
            float2 v2 = __half22float2(xh2[(size_t)e2 * 32 + f]);
            float2 v3 = __half22float2(xh2[(size_t)e3 * 32 + f]);
            ax += (v0.x + v1.x) + (v2.x + v3.x);
            ay += (v0.y + v1.y) + (v2.y + v3.y);
        }
    }
    // combine even/odd half-wave partials
    float sx = ax + __shfl(ax, c ^ 32);
    float sy = ay + __shfl(ay, c ^ 32);
    if (sub == 0) {
        out2[(size_t)r * 32 + f] = make_float2(dr * sx, dr * sy);
    }
}

extern "C" void kernel_launch(void* const* d_in, const int* in_sizes, int n_in,
                              void* d_out, int out_size, void* d_ws, size_t ws_size,
                              hipStream_t stream) {
    const int*   ei = (const int*)d_in[0];   // (2,E) flat: [0..E) rows, [E..2E) cols
    const float* x  = (const float*)d_in[1]; // (N,64)
    const float* W  = (const float*)d_in[2]; // (64,64)
    float* out = (float*)d_out;              // (N,64)

    int E = in_sizes[0] / 2;
    int N = in_sizes[1] / D;
    int nb = (N + 255) / 256;

    // Workspace layout (256 B aligned slices)
    char* p = (char*)d_ws;
    size_t off = 0;
    auto take = [&](size_t bytes) -> char* {
        char* cur = p + off;
        off = (off + bytes + 255) & ~(size_t)255;
        return cur;
    };
    int*    degi    = (int*)take((size_t)N * 4);
    float*  dinv    = (float*)take((size_t)N * 4);
    int*    rowptr  = (int*)take((size_t)N * 4);
    int*    bsum    = (int*)take((size_t)nb * 4);
    int*    csr_col = (int*)take((size_t)E * 4);
    __half* xh      = (__half*)take((size_t)(N + 1) * D * 2);  // +1 sentinel row
    (void)ws_size;

    hipMemsetAsync(degi, 0, (size_t)N * 4, stream);
    hipMemsetAsync(xh + (size_t)N * D, 0, D * sizeof(__half), stream);  // sentinel row = 0

    deg_kernel<<<(E + 255) / 256, 256, 0, stream>>>(ei, E, degi);
    scan_block_sums<<<nb, 256, 0, stream>>>(degi, N, bsum);
    scan_top<<<1, 1024, 0, stream>>>(bsum, nb);
    scan_final<<<nb, 256, 0, stream>>>(degi, N, bsum, rowptr, dinv);
    fill_kernel<<<(E + 255) / 256, 256, 0, stream>>>(ei, E, rowptr, csr_col);
    linear_kernel<<<1024, 256, 0, stream>>>(x, W, dinv, xh, N);
    spmm_kernel<<<(N + 3) / 4, 256, 0, stream>>>(rowptr, csr_col, dinv,
                                                 (const __half2*)xh, (float2*)out, N);
}